// Round 8
// baseline (293.308 us; speedup 1.0000x reference)
//
#include <hip/hip_runtime.h>
#include <cmath>

#define K_SEG 50
#define ITERS 10
#define NPASS (ITERS + 1)       // 10 updates + final labeling pass
#define H_IMG 512
#define W_IMG 512
#define NPIX (H_IMG * W_IMG)
#define BATCH 16
#define SLOTS (K_SEG * 6)       // 300 doubles per image
#define TOTAL_SLOTS (NPASS * BATCH * SLOTS)

// ================= fused-update path =================
// ws: gsums[NPASS][BATCH][SLOTS]  = 422400 B

__global__ void zero_all(double* __restrict__ g) {
    int i = blockIdx.x * 256 + threadIdx.x;
    if (i < TOTAL_SLOTS) g[i] = 0.0;
}

// One pass: compute centers from gsums[it-1] (or grid-init), label a 32x64 tile,
// accumulate per-segment sums into gsums[it].  2048 blocks -> 8/CU occupancy.
__global__ void __launch_bounds__(256) assign_fused(
        const float* __restrict__ x, double* __restrict__ gsums,
        int it, float ratiof) {
    __shared__ float cen[K_SEG][6];     // r,g,b,cy,cx,h2(=0.5*c.c)
    __shared__ float cmax[K_SEG];       // exact per-center max color-dist^2
    __shared__ double part[K_SEG][6];
    __shared__ int klist4[4][52];
    __shared__ int ncand4[4];

    int t = threadIdx.x;
    int tx = blockIdx.x, ty = blockIdx.y, b = blockIdx.z;
    const float* xb = x + (size_t)b * 3 * NPIX;

    // ---- centers for this pass (identical fp32 math in every block) ----
    if (it == 0) {
        if (t < K_SEG) {
            int i = t >> 3, j = t & 7;
            int y = 32 + 64 * i, xc = 32 + 64 * j;   // grid init
            int p = y * W_IMG + xc;
            float r = xb[p], g = xb[NPIX + p], bl = xb[2 * NPIX + p];
            float cfy = (float)y * ratiof, cfx = (float)xc * ratiof;
            cen[t][0]=r; cen[t][1]=g; cen[t][2]=bl; cen[t][3]=cfy; cen[t][4]=cfx;
            cen[t][5] = 0.5f * ((((r*r + g*g) + bl*bl) + cfy*cfy) + cfx*cfx);
            float m0 = fmaxf(r, 1.0f - r), m1 = fmaxf(g, 1.0f - g), m2 = fmaxf(bl, 1.0f - bl);
            cmax[t] = (m0*m0 + m1*m1) + m2*m2;
        }
    } else {
        const double* gp = gsums + ((size_t)(it - 1) * BATCH + b) * SLOTS;
        for (int i = t; i < SLOTS; i += 256) ((double*)part)[i] = gp[i];
        __syncthreads();
        if (t < K_SEG) {
            double cv = part[t][5];
            double denom = cv > 1.0 ? cv : 1.0;
            double rcp = 1.0 / denom;        // one fp64 divide, then 5 muls
            float c0 = (float)(part[t][0] * rcp);
            float c1 = (float)(part[t][1] * rcp);
            float c2v = (float)(part[t][2] * rcp);
            float c3 = (float)(part[t][3] * rcp);
            float c4 = (float)(part[t][4] * rcp);
            cen[t][0]=c0; cen[t][1]=c1; cen[t][2]=c2v; cen[t][3]=c3; cen[t][4]=c4;
            cen[t][5] = 0.5f * ((((c0*c0 + c1*c1) + c2v*c2v) + c3*c3) + c4*c4);
            float m0 = fmaxf(c0, 1.0f - c0), m1 = fmaxf(c1, 1.0f - c1), m2 = fmaxf(c2v, 1.0f - c2v);
            cmax[t] = (m0*m0 + m1*m1) + m2*m2;
        }
    }
    __syncthreads();

    // ---- exact per-WAVE spatial pruning (8-row x 64-col rect) ----
    // argmin uses score = 0.5*c2 - dot (== (d - f2)/2 exactly in reals);
    // prune in d-space: k alive iff Rmin_k <= min_j(Rmax_j + cmax_j) + eps.
    int wid = t >> 6;
    int lane = t & 63;
    {
        float Rmin = INFINITY, val = INFINITY;
        if (lane < K_SEG) {
            float cy = cen[lane][3], cxx = cen[lane][4];
            float y0 = (float)(ty * 32 + wid * 8) * ratiof;
            float y1 = (float)(ty * 32 + wid * 8 + 7) * ratiof;
            float x0 = (float)(tx * 64) * ratiof;
            float x1 = (float)(tx * 64 + 63) * ratiof;
            float dyn = fmaxf(fmaxf(y0 - cy, cy - y1), 0.0f);
            float dxn = fmaxf(fmaxf(x0 - cxx, cxx - x1), 0.0f);
            float dyf = fmaxf(cy - y0, y1 - cy);
            float dxf = fmaxf(cxx - x0, x1 - cxx);
            Rmin = dyn * dyn + dxn * dxn;
            val = (dyf * dyf + dxf * dxf) + cmax[lane];
        }
        float u = val;
        for (int off = 32; off; off >>= 1) u = fminf(u, __shfl_xor(u, off));
        bool cand = (lane < K_SEG) && (Rmin <= u + 0.25f);  // eps >> fp32 rounding
        unsigned long long m = __ballot(cand);
        if (cand) {
            int pos = __popcll(m & ((1ull << lane) - 1ull));
            klist4[wid][pos] = lane;   // ascending k -> argmin first-min tie rule kept
        }
        if (lane == 0) ncand4[wid] = __popcll(m);
    }
    for (int i = t; i < SLOTS; i += 256) ((double*)part)[i] = 0.0;
    __syncthreads();
    int nc = ncand4[wid];

    // ---- labels (8 px per thread) + run-length aggregation + LDS fp64 atomics ----
    int row = t >> 3;                    // 0..31
    int col8 = (t & 7) << 3;             // 0,8,...,56
    int gy = ty * 32 + row;
    int gx = tx * 64 + col8;
    float fy = (float)gy * ratiof;

    size_t p = (size_t)gy * W_IMG + gx;
    float4 ra = *(const float4*)(xb + p);
    float4 rb4 = *(const float4*)(xb + p + 4);
    float4 ga = *(const float4*)(xb + NPIX + p);
    float4 gb4 = *(const float4*)(xb + NPIX + p + 4);
    float4 ba = *(const float4*)(xb + 2 * NPIX + p);
    float4 bb4 = *(const float4*)(xb + 2 * NPIX + p + 4);
    float rr[8] = {ra.x, ra.y, ra.z, ra.w, rb4.x, rb4.y, rb4.z, rb4.w};
    float gg[8] = {ga.x, ga.y, ga.z, ga.w, gb4.x, gb4.y, gb4.z, gb4.w};
    float bv[8] = {ba.x, ba.y, ba.z, ba.w, bb4.x, bb4.y, bb4.z, bb4.w};
    float fx8[8], best8[8];
    int lab8[8];
#pragma unroll
    for (int u2 = 0; u2 < 8; ++u2) {
        fx8[u2] = (float)(gx + u2) * ratiof;
        best8[u2] = INFINITY;
        lab8[u2] = 0;
    }
    for (int c = 0; c < nc; ++c) {
        int k = klist4[wid][c];
        float c0 = cen[k][0], c1 = cen[k][1], c2v = cen[k][2];
        float c3 = cen[k][3], c4 = cen[k][4], h2 = cen[k][5];
        float base = fmaf(fy, -c3, h2);
#pragma unroll
        for (int u2 = 0; u2 < 8; ++u2) {
            float s = fmaf(rr[u2], -c0, base);
            s = fmaf(gg[u2], -c1, s);
            s = fmaf(bv[u2], -c2v, s);
            s = fmaf(fx8[u2], -c4, s);
            if (s < best8[u2]) { best8[u2] = s; lab8[u2] = k; }
        }
    }
    int runlab = -1;
    float sr = 0.0f, sg = 0.0f, sb = 0.0f, sfx = 0.0f;
    int rn = 0;
#pragma unroll
    for (int u2 = 0; u2 < 8; ++u2) {
        if (lab8[u2] != runlab) {
            if (rn > 0) {
                double* pp = part[runlab];
                unsafeAtomicAdd(&pp[0], (double)sr);
                unsafeAtomicAdd(&pp[1], (double)sg);
                unsafeAtomicAdd(&pp[2], (double)sb);
                unsafeAtomicAdd(&pp[3], (double)fy * (double)rn);
                unsafeAtomicAdd(&pp[4], (double)sfx);
                unsafeAtomicAdd(&pp[5], (double)rn);
            }
            runlab = lab8[u2];
            sr = rr[u2]; sg = gg[u2]; sb = bv[u2]; sfx = fx8[u2]; rn = 1;
        } else {
            sr += rr[u2]; sg += gg[u2]; sb += bv[u2]; sfx += fx8[u2]; rn += 1;
        }
    }
    if (rn > 0) {
        double* pp = part[runlab];
        unsafeAtomicAdd(&pp[0], (double)sr);
        unsafeAtomicAdd(&pp[1], (double)sg);
        unsafeAtomicAdd(&pp[2], (double)sb);
        unsafeAtomicAdd(&pp[3], (double)fy * (double)rn);
        unsafeAtomicAdd(&pp[4], (double)sfx);
        unsafeAtomicAdd(&pp[5], (double)rn);
    }
    __syncthreads();

    // ---- flush block partials to this pass's global sums ----
    double* gp = gsums + ((size_t)it * BATCH + b) * SLOTS;
    for (int i = t; i < SLOTS; i += 256) {
        double v = ((double*)part)[i];
        if (v != 0.0) unsafeAtomicAdd(&gp[i], v);
    }
}

__global__ void finalize_kernel(const double* __restrict__ gsums, float* __restrict__ out) {
    int t = threadIdx.x;
    if (t < BATCH) {
        const double* gp = gsums + ((size_t)ITERS * BATCH + t) * SLOTS;
        double sr = 0.0, sg = 0.0, sb = 0.0;
        for (int k = 0; k < K_SEG; ++k) {
            const double* s = gp + k * 6;
            double cv = s[5];
            float cntf = (float)(cv > 1.0 ? cv : 1.0);
            float wf = 1.0f / cntf;  // fp32 rounding like reference w
            sr += s[0] * (double)wf;
            sg += s[1] * (double)wf;
            sb += s[2] * (double)wf;
        }
        double mr = sr / (double)NPIX, mg = sg / (double)NPIX, mb = sb / (double)NPIX;
        double Drg = (mr - mg) * (mr - mg);
        double Drb = (mr - mb) * (mr - mb);
        double Dgb = (mb - mg) * (mb - mg);
        out[t] = (float)sqrt(Drg * Drg + Drb * Drb + Dgb * Dgb);
    }
}

// ================= fallback path (proven R2 sequence, 313us) =================

__global__ void init_kernelF(const float* __restrict__ x, double* __restrict__ gsums,
                             float* __restrict__ centers, float* __restrict__ c2s,
                             float ratiof) {
    int b = blockIdx.x;
    int t = threadIdx.x;
    for (int i = t; i < SLOTS; i += blockDim.x) gsums[b * SLOTS + i] = 0.0;
    if (t < K_SEG) {
        int i = t >> 3, j = t & 7;
        int y = 32 + 64 * i, xc = 32 + 64 * j;
        const float* xb = x + (size_t)b * 3 * NPIX;
        int p = y * W_IMG + xc;
        float r = xb[p], g = xb[NPIX + p], bl = xb[2 * NPIX + p];
        float fyc = (float)y * ratiof, fxc = (float)xc * ratiof;
        float* c = centers + (b * K_SEG + t) * 5;
        c[0] = r; c[1] = g; c[2] = bl; c[3] = fyc; c[4] = fxc;
        c2s[b * K_SEG + t] = (((r * r + g * g) + bl * bl) + fyc * fyc) + fxc * fxc;
    }
}

__global__ void __launch_bounds__(128, 4) assign_kernelF(
        const float* __restrict__ x, double* __restrict__ gsums,
        const float* __restrict__ centers, const float* __restrict__ c2s,
        float ratiof) {
    __shared__ float cen[K_SEG][5];
    __shared__ float c2l[K_SEG];
    __shared__ double part[K_SEG][6];
    __shared__ int klist[K_SEG];
    __shared__ int ncand_s;

    int t = threadIdx.x;
    int tx = blockIdx.x, ty = blockIdx.y, b = blockIdx.z;

    const float* csrc = centers + b * K_SEG * 5;
    for (int i = t; i < K_SEG * 5; i += 128) ((float*)cen)[i] = csrc[i];
    for (int i = t; i < K_SEG; i += 128) c2l[i] = c2s[b * K_SEG + i];
    for (int i = t; i < SLOTS; i += 128) ((double*)part)[i] = 0.0;
    __syncthreads();

    if (t < 64) {
        int k = t;
        float R = INFINITY, val = INFINITY;
        if (k < K_SEG) {
            float cy = cen[k][3], cx = cen[k][4];
            float y0 = (float)(ty * 32) * ratiof;
            float y1 = (float)(ty * 32 + 31) * ratiof;
            float x0 = (float)(tx * 64) * ratiof;
            float x1 = (float)(tx * 64 + 63) * ratiof;
            float dyn = fmaxf(fmaxf(y0 - cy, cy - y1), 0.0f);
            float dxn = fmaxf(fmaxf(x0 - cx, cx - x1), 0.0f);
            float dyf = fmaxf(cy - y0, y1 - cy);
            float dxf = fmaxf(cx - x0, x1 - cx);
            R = dyn * dyn + dxn * dxn;
            val = (dyf * dyf + dxf * dxf) + 3.0f;
        }
        float u = val;
        for (int off = 32; off; off >>= 1) u = fminf(u, __shfl_xor(u, off));
        bool cand = (k < K_SEG) && (R <= u + 4.0f);
        unsigned long long m = __ballot(cand);
        if (cand) {
            int pos = __popcll(m & ((1ull << t) - 1ull));
            klist[pos] = k;
        }
        if (t == 0) ncand_s = __popcll(m);
    }
    __syncthreads();
    int ncand = ncand_s;

    int row = t >> 2;
    int colq = (t & 3) << 4;
    int gy = ty * 32 + row;
    int gx0 = tx * 64 + colq;
    const float* xb = x + (size_t)b * 3 * NPIX;
    float fy = (float)gy * ratiof;

    int runlab = -1;
    float sr = 0.0f, sg = 0.0f, sb = 0.0f, sfx = 0.0f;
    int rn = 0;

    for (int h = 0; h < 2; ++h) {
        int gx = gx0 + h * 8;
        size_t p = (size_t)gy * W_IMG + gx;
        float4 ra = *(const float4*)(xb + p);
        float4 rb4 = *(const float4*)(xb + p + 4);
        float4 ga = *(const float4*)(xb + NPIX + p);
        float4 gb4 = *(const float4*)(xb + NPIX + p + 4);
        float4 ba = *(const float4*)(xb + 2 * NPIX + p);
        float4 bb4 = *(const float4*)(xb + 2 * NPIX + p + 4);
        float rr[8] = {ra.x, ra.y, ra.z, ra.w, rb4.x, rb4.y, rb4.z, rb4.w};
        float gg[8] = {ga.x, ga.y, ga.z, ga.w, gb4.x, gb4.y, gb4.z, gb4.w};
        float bv[8] = {ba.x, ba.y, ba.z, ba.w, bb4.x, bb4.y, bb4.z, bb4.w};
        float fx8[8], f28[8], best8[8];
        int lab8[8];
#pragma unroll
        for (int u2 = 0; u2 < 8; ++u2) {
            fx8[u2] = (float)(gx + u2) * ratiof;
            f28[u2] = (((rr[u2] * rr[u2] + gg[u2] * gg[u2]) + bv[u2] * bv[u2]) + fy * fy) + fx8[u2] * fx8[u2];
            best8[u2] = INFINITY;
            lab8[u2] = 0;
        }
        for (int c = 0; c < ncand; ++c) {
            int k = klist[c];
            float c0 = cen[k][0], c1 = cen[k][1], c2v = cen[k][2], c3 = cen[k][3], c4 = cen[k][4];
            float c2k = c2l[k];
#pragma unroll
            for (int u2 = 0; u2 < 8; ++u2) {
                float dot = rr[u2] * c0 + gg[u2] * c1 + bv[u2] * c2v + fy * c3 + fx8[u2] * c4;
                float d = (f28[u2] + c2k) - 2.0f * dot;
                if (d < best8[u2]) { best8[u2] = d; lab8[u2] = k; }
            }
        }
#pragma unroll
        for (int u2 = 0; u2 < 8; ++u2) {
            if (lab8[u2] != runlab) {
                if (rn > 0) {
                    double* pp = part[runlab];
                    unsafeAtomicAdd(&pp[0], (double)sr);
                    unsafeAtomicAdd(&pp[1], (double)sg);
                    unsafeAtomicAdd(&pp[2], (double)sb);
                    unsafeAtomicAdd(&pp[3], (double)fy * (double)rn);
                    unsafeAtomicAdd(&pp[4], (double)sfx);
                    unsafeAtomicAdd(&pp[5], (double)rn);
                }
                runlab = lab8[u2];
                sr = rr[u2]; sg = gg[u2]; sb = bv[u2]; sfx = fx8[u2]; rn = 1;
            } else {
                sr += rr[u2]; sg += gg[u2]; sb += bv[u2]; sfx += fx8[u2]; rn += 1;
            }
        }
    }
    if (rn > 0) {
        double* pp = part[runlab];
        unsafeAtomicAdd(&pp[0], (double)sr);
        unsafeAtomicAdd(&pp[1], (double)sg);
        unsafeAtomicAdd(&pp[2], (double)sb);
        unsafeAtomicAdd(&pp[3], (double)fy * (double)rn);
        unsafeAtomicAdd(&pp[4], (double)sfx);
        unsafeAtomicAdd(&pp[5], (double)rn);
    }
    __syncthreads();
    for (int i = t; i < SLOTS; i += 128) {
        double v = ((double*)part)[i];
        if (v != 0.0) unsafeAtomicAdd(&gsums[b * SLOTS + i], v);
    }
}

__global__ void update_kernelF(double* __restrict__ gsums, float* __restrict__ centers,
                               float* __restrict__ c2s) {
    int b = blockIdx.x;
    int t = threadIdx.x;
    if (t < K_SEG) {
        double* s = gsums + (b * K_SEG + t) * 6;
        double cv = s[5];
        double denom = cv > 1.0 ? cv : 1.0;
        float c[5];
#pragma unroll
        for (int j = 0; j < 5; ++j) { c[j] = (float)(s[j] / denom); s[j] = 0.0; }
        s[5] = 0.0;
        float* cd = centers + (b * K_SEG + t) * 5;
#pragma unroll
        for (int j = 0; j < 5; ++j) cd[j] = c[j];
        c2s[b * K_SEG + t] = (((c[0] * c[0] + c[1] * c[1]) + c[2] * c[2]) + c[3] * c[3]) + c[4] * c[4];
    }
}

__global__ void finalize_kernelF(const double* __restrict__ gsums, float* __restrict__ out) {
    int t = threadIdx.x;
    if (t < BATCH) {
        double sr = 0.0, sg = 0.0, sb = 0.0;
        for (int k = 0; k < K_SEG; ++k) {
            const double* s = gsums + (t * K_SEG + k) * 6;
            double cv = s[5];
            float cntf = (float)(cv > 1.0 ? cv : 1.0);
            float wf = 1.0f / cntf;
            sr += s[0] * (double)wf;
            sg += s[1] * (double)wf;
            sb += s[2] * (double)wf;
        }
        double mr = sr / (double)NPIX, mg = sg / (double)NPIX, mb = sb / (double)NPIX;
        double Drg = (mr - mg) * (mr - mg);
        double Drb = (mr - mb) * (mr - mb);
        double Dgb = (mb - mg) * (mb - mg);
        out[t] = (float)sqrt(Drg * Drg + Drb * Drb + Dgb * Dgb);
    }
}

extern "C" void kernel_launch(void* const* d_in, const int* in_sizes, int n_in,
                              void* d_out, int out_size, void* d_ws, size_t ws_size,
                              hipStream_t stream) {
    const float* x = (const float*)d_in[0];
    float* out = (float*)d_out;
    char* ws = (char*)d_ws;

    double S = sqrt((double)NPIX / (double)K_SEG);
    float ratiof = (float)(10.0 / S);

    if (ws_size >= (size_t)TOTAL_SLOTS * sizeof(double)) {
        double* gsums = (double*)ws;
        zero_all<<<(TOTAL_SLOTS + 255) / 256, 256, 0, stream>>>(gsums);
        dim3 agrid(W_IMG / 64, H_IMG / 32, BATCH);   // 2048 blocks
        for (int it = 0; it < NPASS; ++it)
            assign_fused<<<agrid, 256, 0, stream>>>(x, gsums, it, ratiof);
        finalize_kernel<<<1, 64, 0, stream>>>(gsums, out);
        return;
    }

    // fallback: R2's proven 313us sequence
    const size_t gbytes = (size_t)BATCH * SLOTS * sizeof(double);
    double* gsums = (double*)ws;
    float* centers = (float*)(ws + gbytes);
    float* c2s = (float*)(ws + gbytes + (size_t)BATCH * K_SEG * 5 * 4);

    init_kernelF<<<BATCH, 64, 0, stream>>>(x, gsums, centers, c2s, ratiof);
    dim3 agrid(W_IMG / 64, H_IMG / 32, BATCH);
    for (int it = 0; it < ITERS; ++it) {
        assign_kernelF<<<agrid, 128, 0, stream>>>(x, gsums, centers, c2s, ratiof);
        update_kernelF<<<BATCH, 64, 0, stream>>>(gsums, centers, c2s);
    }
    assign_kernelF<<<agrid, 128, 0, stream>>>(x, gsums, centers, c2s, ratiof);
    finalize_kernelF<<<1, 64, 0, stream>>>(gsums, out);
}

// Round 9
// 213.714 us; speedup vs baseline: 1.3724x; 1.3724x over previous
//
#include <hip/hip_runtime.h>
#include <cmath>

#define K_SEG 50
#define ITERS 10
#define NPASS (ITERS + 1)       // 10 updates + final labeling pass
#define H_IMG 512
#define W_IMG 512
#define NPIX (H_IMG * W_IMG)
#define BATCH 16
#define SLOTS (K_SEG * 6)       // 300 doubles per image
#define TOTAL_SLOTS (NPASS * BATCH * SLOTS)

// ================= fused-update path =================
// ws: gsums[NPASS][BATCH][SLOTS]  = 422400 B
// part/gsums slot layout: [0]=r [1]=g [2]=b [3]=SUM(row) [4]=SUM(col) [5]=count
// (rows/cols are exact small ints; multiplied by ratiof once at block flush)

__global__ void zero_all(double* __restrict__ g) {
    int i = blockIdx.x * 256 + threadIdx.x;
    if (i < TOTAL_SLOTS) g[i] = 0.0;
}

__global__ void __launch_bounds__(256) assign_fused(
        const float* __restrict__ x, double* __restrict__ gsums,
        int it, float ratiof) {
    __shared__ float cen[K_SEG][6];     // r,g,b,cy,cx,h2(=0.5*c.c)
    __shared__ float cmax[K_SEG];       // exact per-center max color-dist^2
    __shared__ double part[K_SEG][6];
    __shared__ int klist4[4][52];
    __shared__ int ncand4[4];

    int t = threadIdx.x;
    int tx = blockIdx.x, ty = blockIdx.y, b = blockIdx.z;
    const float* xb = x + (size_t)b * 3 * NPIX;

    // ---- centers for this pass (identical fp32 math in every block) ----
    if (it == 0) {
        if (t < K_SEG) {
            int i = t >> 3, j = t & 7;
            int y = 32 + 64 * i, xc = 32 + 64 * j;   // grid init
            int p = y * W_IMG + xc;
            float r = xb[p], g = xb[NPIX + p], bl = xb[2 * NPIX + p];
            float cfy = (float)y * ratiof, cfx = (float)xc * ratiof;
            cen[t][0]=r; cen[t][1]=g; cen[t][2]=bl; cen[t][3]=cfy; cen[t][4]=cfx;
            cen[t][5] = 0.5f * ((((r*r + g*g) + bl*bl) + cfy*cfy) + cfx*cfx);
            float m0 = fmaxf(r, 1.0f - r), m1 = fmaxf(g, 1.0f - g), m2 = fmaxf(bl, 1.0f - bl);
            cmax[t] = (m0*m0 + m1*m1) + m2*m2;
        }
    } else {
        const double* gp = gsums + ((size_t)(it - 1) * BATCH + b) * SLOTS;
        for (int i = t; i < SLOTS; i += 256) ((double*)part)[i] = gp[i];
        __syncthreads();
        if (t < K_SEG) {
            double cv = part[t][5];
            double denom = cv > 1.0 ? cv : 1.0;
            double rcp = 1.0 / denom;        // one fp64 divide, then 5 muls
            float c0 = (float)(part[t][0] * rcp);
            float c1 = (float)(part[t][1] * rcp);
            float c2v = (float)(part[t][2] * rcp);
            float c3 = (float)(part[t][3] * rcp);
            float c4 = (float)(part[t][4] * rcp);
            cen[t][0]=c0; cen[t][1]=c1; cen[t][2]=c2v; cen[t][3]=c3; cen[t][4]=c4;
            cen[t][5] = 0.5f * ((((c0*c0 + c1*c1) + c2v*c2v) + c3*c3) + c4*c4);
            float m0 = fmaxf(c0, 1.0f - c0), m1 = fmaxf(c1, 1.0f - c1), m2 = fmaxf(c2v, 1.0f - c2v);
            cmax[t] = (m0*m0 + m1*m1) + m2*m2;
        }
    }
    __syncthreads();

    // ---- exact per-WAVE spatial pruning (16-row x 64-col rect) ----
    int wid = t >> 6;
    int lane = t & 63;
    {
        float Rmin = INFINITY, val = INFINITY;
        if (lane < K_SEG) {
            float cy = cen[lane][3], cxx = cen[lane][4];
            float y0 = (float)(ty * 64 + wid * 16) * ratiof;
            float y1 = (float)(ty * 64 + wid * 16 + 15) * ratiof;
            float x0 = (float)(tx * 64) * ratiof;
            float x1 = (float)(tx * 64 + 63) * ratiof;
            float dyn = fmaxf(fmaxf(y0 - cy, cy - y1), 0.0f);
            float dxn = fmaxf(fmaxf(x0 - cxx, cxx - x1), 0.0f);
            float dyf = fmaxf(cy - y0, y1 - cy);
            float dxf = fmaxf(cxx - x0, x1 - cxx);
            Rmin = dyn * dyn + dxn * dxn;
            val = (dyf * dyf + dxf * dxf) + cmax[lane];
        }
        float u = val;
        for (int off = 32; off; off >>= 1) u = fminf(u, __shfl_xor(u, off));
        bool cand = (lane < K_SEG) && (Rmin <= u + 0.25f);  // eps >> fp32 rounding
        unsigned long long m = __ballot(cand);
        if (cand) {
            int pos = __popcll(m & ((1ull << lane) - 1ull));
            klist4[wid][pos] = lane;   // ascending k -> argmin first-min tie rule kept
        }
        if (lane == 0) ncand4[wid] = __popcll(m);
    }
    for (int i = t; i < SLOTS; i += 256) ((double*)part)[i] = 0.0;
    __syncthreads();
    int nc = ncand4[wid];

    // ---- labels (16 px/thread in 2 halves) + run accumulation ----
    int row = t >> 2;                 // 0..63 within tile; wave = rows 16w..16w+15
    int colq = (t & 3) << 4;
    int gy = ty * 64 + row;
    int gx0 = tx * 64 + colq;
    float fy = (float)gy * ratiof;

    int runlab = -1;
    float sr = 0.0f, sg = 0.0f, sb = 0.0f, scol = 0.0f;
    int rn = 0;
    for (int h = 0; h < 2; ++h) {
        int gx = gx0 + h * 8;
        size_t p = (size_t)gy * W_IMG + gx;
        float4 ra = *(const float4*)(xb + p);
        float4 rb4 = *(const float4*)(xb + p + 4);
        float4 ga = *(const float4*)(xb + NPIX + p);
        float4 gb4 = *(const float4*)(xb + NPIX + p + 4);
        float4 ba = *(const float4*)(xb + 2 * NPIX + p);
        float4 bb4 = *(const float4*)(xb + 2 * NPIX + p + 4);
        float rr[8] = {ra.x, ra.y, ra.z, ra.w, rb4.x, rb4.y, rb4.z, rb4.w};
        float gg[8] = {ga.x, ga.y, ga.z, ga.w, gb4.x, gb4.y, gb4.z, gb4.w};
        float bv[8] = {ba.x, ba.y, ba.z, ba.w, bb4.x, bb4.y, bb4.z, bb4.w};
        float fx8[8], best8[8];
        int lab8[8];
#pragma unroll
        for (int u2 = 0; u2 < 8; ++u2) {
            fx8[u2] = (float)(gx + u2) * ratiof;   // same expr as before: labels identical
            best8[u2] = INFINITY;
            lab8[u2] = 0;
        }
        for (int c = 0; c < nc; ++c) {
            int k = klist4[wid][c];
            float c0 = cen[k][0], c1 = cen[k][1], c2v = cen[k][2];
            float c3 = cen[k][3], c4 = cen[k][4], h2 = cen[k][5];
            float base = fmaf(fy, -c3, h2);
#pragma unroll
            for (int u2 = 0; u2 < 8; ++u2) {
                float s = fmaf(rr[u2], -c0, base);
                s = fmaf(gg[u2], -c1, s);
                s = fmaf(bv[u2], -c2v, s);
                s = fmaf(fx8[u2], -c4, s);
                if (s < best8[u2]) { best8[u2] = s; lab8[u2] = k; }
            }
        }
#pragma unroll
        for (int u2 = 0; u2 < 8; ++u2) {
            if (lab8[u2] != runlab) {
                if (rn > 0) {   // mid-thread run boundary: rare inline flush
                    double* pp = part[runlab];
                    unsafeAtomicAdd(&pp[0], (double)sr);
                    unsafeAtomicAdd(&pp[1], (double)sg);
                    unsafeAtomicAdd(&pp[2], (double)sb);
                    unsafeAtomicAdd(&pp[3], (double)((float)(gy * rn)));  // exact int
                    unsafeAtomicAdd(&pp[4], (double)scol);                 // exact int
                    unsafeAtomicAdd(&pp[5], (double)rn);
                }
                runlab = lab8[u2];
                sr = rr[u2]; sg = gg[u2]; sb = bv[u2]; scol = (float)(gx + u2); rn = 1;
            } else {
                sr += rr[u2]; sg += gg[u2]; sb += bv[u2]; scol += (float)(gx + u2); rn += 1;
            }
        }
    }

    // ---- wave-segmented reduction of final runs (2-4 distinct labels/wave) ----
    {
        float fsr = sr, fsg = sg, fsb = sb, fscol = scol;
        float fsrow = (float)(gy * rn);     // <= 511*16, exact
        float frn = (float)rn;
        unsigned long long remaining = __ballot(true);
        while (remaining) {
            int leader = __ffsll((unsigned long long)remaining) - 1;
            int labL = __shfl(runlab, leader);
            bool in = (runlab == labL);
            unsigned long long grp = __ballot(in);
            float a0 = in ? fsr : 0.0f, a1 = in ? fsg : 0.0f, a2 = in ? fsb : 0.0f;
            float a3 = in ? fsrow : 0.0f, a4 = in ? fscol : 0.0f, a5 = in ? frn : 0.0f;
#pragma unroll
            for (int off = 1; off < 64; off <<= 1) {
                a0 += __shfl_xor(a0, off);
                a1 += __shfl_xor(a1, off);
                a2 += __shfl_xor(a2, off);
                a3 += __shfl_xor(a3, off);
                a4 += __shfl_xor(a4, off);
                a5 += __shfl_xor(a5, off);
            }
            if (lane == leader) {
                double* pp = part[labL];
                unsafeAtomicAdd(&pp[0], (double)a0);
                unsafeAtomicAdd(&pp[1], (double)a1);
                unsafeAtomicAdd(&pp[2], (double)a2);
                unsafeAtomicAdd(&pp[3], (double)a3);
                unsafeAtomicAdd(&pp[4], (double)a4);
                unsafeAtomicAdd(&pp[5], (double)a5);
            }
            remaining &= ~grp;
        }
    }
    __syncthreads();

    // ---- flush block partials to this pass's global sums (scale row/col) ----
    double* gp = gsums + ((size_t)it * BATCH + b) * SLOTS;
    for (int i = t; i < SLOTS; i += 256) {
        double v = ((double*)part)[i];
        int slot = i % 6;
        if (slot == 3 || slot == 4) v *= (double)ratiof;
        if (v != 0.0) unsafeAtomicAdd(&gp[i], v);
    }
}

__global__ void finalize_kernel(const double* __restrict__ gsums, float* __restrict__ out) {
    int t = threadIdx.x;
    if (t < BATCH) {
        const double* gp = gsums + ((size_t)ITERS * BATCH + t) * SLOTS;
        double sr = 0.0, sg = 0.0, sb = 0.0;
        for (int k = 0; k < K_SEG; ++k) {
            const double* s = gp + k * 6;
            double cv = s[5];
            float cntf = (float)(cv > 1.0 ? cv : 1.0);
            float wf = 1.0f / cntf;  // fp32 rounding like reference w
            sr += s[0] * (double)wf;
            sg += s[1] * (double)wf;
            sb += s[2] * (double)wf;
        }
        double mr = sr / (double)NPIX, mg = sg / (double)NPIX, mb = sb / (double)NPIX;
        double Drg = (mr - mg) * (mr - mg);
        double Drb = (mr - mb) * (mr - mb);
        double Dgb = (mb - mg) * (mb - mg);
        out[t] = (float)sqrt(Drg * Drg + Drb * Drb + Dgb * Dgb);
    }
}

// ================= fallback path (proven R2 sequence, 313us) =================

__global__ void init_kernelF(const float* __restrict__ x, double* __restrict__ gsums,
                             float* __restrict__ centers, float* __restrict__ c2s,
                             float ratiof) {
    int b = blockIdx.x;
    int t = threadIdx.x;
    for (int i = t; i < SLOTS; i += blockDim.x) gsums[b * SLOTS + i] = 0.0;
    if (t < K_SEG) {
        int i = t >> 3, j = t & 7;
        int y = 32 + 64 * i, xc = 32 + 64 * j;
        const float* xb = x + (size_t)b * 3 * NPIX;
        int p = y * W_IMG + xc;
        float r = xb[p], g = xb[NPIX + p], bl = xb[2 * NPIX + p];
        float fyc = (float)y * ratiof, fxc = (float)xc * ratiof;
        float* c = centers + (b * K_SEG + t) * 5;
        c[0] = r; c[1] = g; c[2] = bl; c[3] = fyc; c[4] = fxc;
        c2s[b * K_SEG + t] = (((r * r + g * g) + bl * bl) + fyc * fyc) + fxc * fxc;
    }
}

__global__ void __launch_bounds__(128, 4) assign_kernelF(
        const float* __restrict__ x, double* __restrict__ gsums,
        const float* __restrict__ centers, const float* __restrict__ c2s,
        float ratiof) {
    __shared__ float cen[K_SEG][5];
    __shared__ float c2l[K_SEG];
    __shared__ double part[K_SEG][6];
    __shared__ int klist[K_SEG];
    __shared__ int ncand_s;

    int t = threadIdx.x;
    int tx = blockIdx.x, ty = blockIdx.y, b = blockIdx.z;

    const float* csrc = centers + b * K_SEG * 5;
    for (int i = t; i < K_SEG * 5; i += 128) ((float*)cen)[i] = csrc[i];
    for (int i = t; i < K_SEG; i += 128) c2l[i] = c2s[b * K_SEG + i];
    for (int i = t; i < SLOTS; i += 128) ((double*)part)[i] = 0.0;
    __syncthreads();

    if (t < 64) {
        int k = t;
        float R = INFINITY, val = INFINITY;
        if (k < K_SEG) {
            float cy = cen[k][3], cx = cen[k][4];
            float y0 = (float)(ty * 32) * ratiof;
            float y1 = (float)(ty * 32 + 31) * ratiof;
            float x0 = (float)(tx * 64) * ratiof;
            float x1 = (float)(tx * 64 + 63) * ratiof;
            float dyn = fmaxf(fmaxf(y0 - cy, cy - y1), 0.0f);
            float dxn = fmaxf(fmaxf(x0 - cx, cx - x1), 0.0f);
            float dyf = fmaxf(cy - y0, y1 - cy);
            float dxf = fmaxf(cx - x0, x1 - cx);
            R = dyn * dyn + dxn * dxn;
            val = (dyf * dyf + dxf * dxf) + 3.0f;
        }
        float u = val;
        for (int off = 32; off; off >>= 1) u = fminf(u, __shfl_xor(u, off));
        bool cand = (k < K_SEG) && (R <= u + 4.0f);
        unsigned long long m = __ballot(cand);
        if (cand) {
            int pos = __popcll(m & ((1ull << t) - 1ull));
            klist[pos] = k;
        }
        if (t == 0) ncand_s = __popcll(m);
    }
    __syncthreads();
    int ncand = ncand_s;

    int row = t >> 2;
    int colq = (t & 3) << 4;
    int gy = ty * 32 + row;
    int gx0 = tx * 64 + colq;
    const float* xb = x + (size_t)b * 3 * NPIX;
    float fy = (float)gy * ratiof;

    int runlab = -1;
    float sr = 0.0f, sg = 0.0f, sb = 0.0f, sfx = 0.0f;
    int rn = 0;

    for (int h = 0; h < 2; ++h) {
        int gx = gx0 + h * 8;
        size_t p = (size_t)gy * W_IMG + gx;
        float4 ra = *(const float4*)(xb + p);
        float4 rb4 = *(const float4*)(xb + p + 4);
        float4 ga = *(const float4*)(xb + NPIX + p);
        float4 gb4 = *(const float4*)(xb + NPIX + p + 4);
        float4 ba = *(const float4*)(xb + 2 * NPIX + p);
        float4 bb4 = *(const float4*)(xb + 2 * NPIX + p + 4);
        float rr[8] = {ra.x, ra.y, ra.z, ra.w, rb4.x, rb4.y, rb4.z, rb4.w};
        float gg[8] = {ga.x, ga.y, ga.z, ga.w, gb4.x, gb4.y, gb4.z, gb4.w};
        float bv[8] = {ba.x, ba.y, ba.z, ba.w, bb4.x, bb4.y, bb4.z, bb4.w};
        float fx8[8], f28[8], best8[8];
        int lab8[8];
#pragma unroll
        for (int u2 = 0; u2 < 8; ++u2) {
            fx8[u2] = (float)(gx + u2) * ratiof;
            f28[u2] = (((rr[u2] * rr[u2] + gg[u2] * gg[u2]) + bv[u2] * bv[u2]) + fy * fy) + fx8[u2] * fx8[u2];
            best8[u2] = INFINITY;
            lab8[u2] = 0;
        }
        for (int c = 0; c < ncand; ++c) {
            int k = klist[c];
            float c0 = cen[k][0], c1 = cen[k][1], c2v = cen[k][2], c3 = cen[k][3], c4 = cen[k][4];
            float c2k = c2l[k];
#pragma unroll
            for (int u2 = 0; u2 < 8; ++u2) {
                float dot = rr[u2] * c0 + gg[u2] * c1 + bv[u2] * c2v + fy * c3 + fx8[u2] * c4;
                float d = (f28[u2] + c2k) - 2.0f * dot;
                if (d < best8[u2]) { best8[u2] = d; lab8[u2] = k; }
            }
        }
#pragma unroll
        for (int u2 = 0; u2 < 8; ++u2) {
            if (lab8[u2] != runlab) {
                if (rn > 0) {
                    double* pp = part[runlab];
                    unsafeAtomicAdd(&pp[0], (double)sr);
                    unsafeAtomicAdd(&pp[1], (double)sg);
                    unsafeAtomicAdd(&pp[2], (double)sb);
                    unsafeAtomicAdd(&pp[3], (double)fy * (double)rn);
                    unsafeAtomicAdd(&pp[4], (double)sfx);
                    unsafeAtomicAdd(&pp[5], (double)rn);
                }
                runlab = lab8[u2];
                sr = rr[u2]; sg = gg[u2]; sb = bv[u2]; sfx = fx8[u2]; rn = 1;
            } else {
                sr += rr[u2]; sg += gg[u2]; sb += bv[u2]; sfx += fx8[u2]; rn += 1;
            }
        }
    }
    if (rn > 0) {
        double* pp = part[runlab];
        unsafeAtomicAdd(&pp[0], (double)sr);
        unsafeAtomicAdd(&pp[1], (double)sg);
        unsafeAtomicAdd(&pp[2], (double)sb);
        unsafeAtomicAdd(&pp[3], (double)fy * (double)rn);
        unsafeAtomicAdd(&pp[4], (double)sfx);
        unsafeAtomicAdd(&pp[5], (double)rn);
    }
    __syncthreads();
    for (int i = t; i < SLOTS; i += 128) {
        double v = ((double*)part)[i];
        if (v != 0.0) unsafeAtomicAdd(&gsums[b * SLOTS + i], v);
    }
}

__global__ void update_kernelF(double* __restrict__ gsums, float* __restrict__ centers,
                               float* __restrict__ c2s) {
    int b = blockIdx.x;
    int t = threadIdx.x;
    if (t < K_SEG) {
        double* s = gsums + (b * K_SEG + t) * 6;
        double cv = s[5];
        double denom = cv > 1.0 ? cv : 1.0;
        float c[5];
#pragma unroll
        for (int j = 0; j < 5; ++j) { c[j] = (float)(s[j] / denom); s[j] = 0.0; }
        s[5] = 0.0;
        float* cd = centers + (b * K_SEG + t) * 5;
#pragma unroll
        for (int j = 0; j < 5; ++j) cd[j] = c[j];
        c2s[b * K_SEG + t] = (((c[0] * c[0] + c[1] * c[1]) + c[2] * c[2]) + c[3] * c[3]) + c[4] * c[4];
    }
}

__global__ void finalize_kernelF(const double* __restrict__ gsums, float* __restrict__ out) {
    int t = threadIdx.x;
    if (t < BATCH) {
        double sr = 0.0, sg = 0.0, sb = 0.0;
        for (int k = 0; k < K_SEG; ++k) {
            const double* s = gsums + (t * K_SEG + k) * 6;
            double cv = s[5];
            float cntf = (float)(cv > 1.0 ? cv : 1.0);
            float wf = 1.0f / cntf;
            sr += s[0] * (double)wf;
            sg += s[1] * (double)wf;
            sb += s[2] * (double)wf;
        }
        double mr = sr / (double)NPIX, mg = sg / (double)NPIX, mb = sb / (double)NPIX;
        double Drg = (mr - mg) * (mr - mg);
        double Drb = (mr - mb) * (mr - mb);
        double Dgb = (mb - mg) * (mb - mg);
        out[t] = (float)sqrt(Drg * Drg + Drb * Drb + Dgb * Dgb);
    }
}

extern "C" void kernel_launch(void* const* d_in, const int* in_sizes, int n_in,
                              void* d_out, int out_size, void* d_ws, size_t ws_size,
                              hipStream_t stream) {
    const float* x = (const float*)d_in[0];
    float* out = (float*)d_out;
    char* ws = (char*)d_ws;

    double S = sqrt((double)NPIX / (double)K_SEG);
    float ratiof = (float)(10.0 / S);

    if (ws_size >= (size_t)TOTAL_SLOTS * sizeof(double)) {
        double* gsums = (double*)ws;
        zero_all<<<(TOTAL_SLOTS + 255) / 256, 256, 0, stream>>>(gsums);
        dim3 agrid(W_IMG / 64, H_IMG / 64, BATCH);   // 1024 blocks (R7 geometry)
        for (int it = 0; it < NPASS; ++it)
            assign_fused<<<agrid, 256, 0, stream>>>(x, gsums, it, ratiof);
        finalize_kernel<<<1, 64, 0, stream>>>(gsums, out);
        return;
    }

    // fallback: R2's proven 313us sequence
    const size_t gbytes = (size_t)BATCH * SLOTS * sizeof(double);
    double* gsums = (double*)ws;
    float* centers = (float*)(ws + gbytes);
    float* c2s = (float*)(ws + gbytes + (size_t)BATCH * K_SEG * 5 * 4);

    init_kernelF<<<BATCH, 64, 0, stream>>>(x, gsums, centers, c2s, ratiof);
    dim3 agrid(W_IMG / 64, H_IMG / 32, BATCH);
    for (int it = 0; it < ITERS; ++it) {
        assign_kernelF<<<agrid, 128, 0, stream>>>(x, gsums, centers, c2s, ratiof);
        update_kernelF<<<BATCH, 64, 0, stream>>>(gsums, centers, c2s);
    }
    assign_kernelF<<<agrid, 128, 0, stream>>>(x, gsums, centers, c2s, ratiof);
    finalize_kernelF<<<1, 64, 0, stream>>>(gsums, out);
}

// Round 10
// 213.084 us; speedup vs baseline: 1.3765x; 1.0030x over previous
//
#include <hip/hip_runtime.h>
#include <cmath>

#define K_SEG 50
#define ITERS 10
#define NPASS (ITERS + 1)       // 10 updates + final labeling pass
#define H_IMG 512
#define W_IMG 512
#define NPIX (H_IMG * W_IMG)
#define BATCH 16
#define SLOTS (K_SEG * 6)       // 300 doubles per image
#define TOTAL_SLOTS (NPASS * BATCH * SLOTS)
#define BLK_PER_IMG 64
#define GRID_BLKS (BATCH * BLK_PER_IMG)

// ws layout:
//   gsums : double[NPASS][BATCH][SLOTS]   422400 B
//   cnt   : uint  [NPASS][BATCH]             704 B  (per-image barrier counters)
// slot layout: [0]=r [1]=g [2]=b [3]=SUM(row) [4]=SUM(col) [5]=count
// (rows/cols exact small ints in fp32 sums; scaled by ratiof at block flush)

__global__ void zero_ws(unsigned* __restrict__ w, int nwords) {
    int i = blockIdx.x * 256 + threadIdx.x;
    if (i < nwords) w[i] = 0u;
}

// ---- shared body: one k-means pass for one 64x64 tile ----
// Identical fp32/fp64 expressions in persist and multi-kernel paths.
__device__ __forceinline__ void pass_body(
        const float* __restrict__ xb, double* __restrict__ gsums,
        int it, int b, int tx, int ty, int t, float ratiof,
        float (*cen)[6], float* cmax, double (*part)[6],
        int (*klist4)[52], int* ncand4) {
    // ---- centers for this pass (identical fp32 math in every block) ----
    if (it == 0) {
        if (t < K_SEG) {
            int i = t >> 3, j = t & 7;
            int y = 32 + 64 * i, xc = 32 + 64 * j;   // grid init
            int p = y * W_IMG + xc;
            float r = xb[p], g = xb[NPIX + p], bl = xb[2 * NPIX + p];
            float cfy = (float)y * ratiof, cfx = (float)xc * ratiof;
            cen[t][0]=r; cen[t][1]=g; cen[t][2]=bl; cen[t][3]=cfy; cen[t][4]=cfx;
            cen[t][5] = 0.5f * ((((r*r + g*g) + bl*bl) + cfy*cfy) + cfx*cfx);
            float m0 = fmaxf(r, 1.0f - r), m1 = fmaxf(g, 1.0f - g), m2 = fmaxf(bl, 1.0f - bl);
            cmax[t] = (m0*m0 + m1*m1) + m2*m2;
        }
    } else {
        const double* gp = gsums + ((size_t)(it - 1) * BATCH + b) * SLOTS;
        for (int i = t; i < SLOTS; i += 256) ((double*)part)[i] = gp[i];
        __syncthreads();
        if (t < K_SEG) {
            double cv = part[t][5];
            double denom = cv > 1.0 ? cv : 1.0;
            double rcp = 1.0 / denom;        // one fp64 divide, then 5 muls
            float c0 = (float)(part[t][0] * rcp);
            float c1 = (float)(part[t][1] * rcp);
            float c2v = (float)(part[t][2] * rcp);
            float c3 = (float)(part[t][3] * rcp);
            float c4 = (float)(part[t][4] * rcp);
            cen[t][0]=c0; cen[t][1]=c1; cen[t][2]=c2v; cen[t][3]=c3; cen[t][4]=c4;
            cen[t][5] = 0.5f * ((((c0*c0 + c1*c1) + c2v*c2v) + c3*c3) + c4*c4);
            float m0 = fmaxf(c0, 1.0f - c0), m1 = fmaxf(c1, 1.0f - c1), m2 = fmaxf(c2v, 1.0f - c2v);
            cmax[t] = (m0*m0 + m1*m1) + m2*m2;
        }
    }
    __syncthreads();

    // ---- exact per-WAVE spatial pruning (16-row x 64-col rect) ----
    int wid = t >> 6;
    int lane = t & 63;
    {
        float Rmin = INFINITY, val = INFINITY;
        if (lane < K_SEG) {
            float cy = cen[lane][3], cxx = cen[lane][4];
            float y0 = (float)(ty * 64 + wid * 16) * ratiof;
            float y1 = (float)(ty * 64 + wid * 16 + 15) * ratiof;
            float x0 = (float)(tx * 64) * ratiof;
            float x1 = (float)(tx * 64 + 63) * ratiof;
            float dyn = fmaxf(fmaxf(y0 - cy, cy - y1), 0.0f);
            float dxn = fmaxf(fmaxf(x0 - cxx, cxx - x1), 0.0f);
            float dyf = fmaxf(cy - y0, y1 - cy);
            float dxf = fmaxf(cxx - x0, x1 - cxx);
            Rmin = dyn * dyn + dxn * dxn;
            val = (dyf * dyf + dxf * dxf) + cmax[lane];
        }
        float u = val;
        for (int off = 32; off; off >>= 1) u = fminf(u, __shfl_xor(u, off));
        bool cand = (lane < K_SEG) && (Rmin <= u + 0.25f);  // eps >> fp32 rounding
        unsigned long long m = __ballot(cand);
        if (cand) {
            int pos = __popcll(m & ((1ull << lane) - 1ull));
            klist4[wid][pos] = lane;   // ascending k -> argmin first-min tie rule kept
        }
        if (lane == 0) ncand4[wid] = __popcll(m);
    }
    for (int i = t; i < SLOTS; i += 256) ((double*)part)[i] = 0.0;
    __syncthreads();
    int nc = ncand4[wid];

    // ---- labels (16 px/thread in 2 halves) + run accumulation ----
    int row = t >> 2;
    int colq = (t & 3) << 4;
    int gy = ty * 64 + row;
    int gx0 = tx * 64 + colq;
    float fy = (float)gy * ratiof;

    int runlab = -1;
    float sr = 0.0f, sg = 0.0f, sb = 0.0f, scol = 0.0f;
    int rn = 0;
    for (int h = 0; h < 2; ++h) {
        int gx = gx0 + h * 8;
        size_t p = (size_t)gy * W_IMG + gx;
        float4 ra = *(const float4*)(xb + p);
        float4 rb4 = *(const float4*)(xb + p + 4);
        float4 ga = *(const float4*)(xb + NPIX + p);
        float4 gb4 = *(const float4*)(xb + NPIX + p + 4);
        float4 ba = *(const float4*)(xb + 2 * NPIX + p);
        float4 bb4 = *(const float4*)(xb + 2 * NPIX + p + 4);
        float rr[8] = {ra.x, ra.y, ra.z, ra.w, rb4.x, rb4.y, rb4.z, rb4.w};
        float gg[8] = {ga.x, ga.y, ga.z, ga.w, gb4.x, gb4.y, gb4.z, gb4.w};
        float bv[8] = {ba.x, ba.y, ba.z, ba.w, bb4.x, bb4.y, bb4.z, bb4.w};
        float fx8[8], best8[8];
        int lab8[8];
#pragma unroll
        for (int u2 = 0; u2 < 8; ++u2) {
            fx8[u2] = (float)(gx + u2) * ratiof;
            best8[u2] = INFINITY;
            lab8[u2] = 0;
        }
        for (int c = 0; c < nc; ++c) {
            int k = klist4[wid][c];
            float c0 = cen[k][0], c1 = cen[k][1], c2v = cen[k][2];
            float c3 = cen[k][3], c4 = cen[k][4], h2 = cen[k][5];
            float base = fmaf(fy, -c3, h2);
#pragma unroll
            for (int u2 = 0; u2 < 8; ++u2) {
                float s = fmaf(rr[u2], -c0, base);
                s = fmaf(gg[u2], -c1, s);
                s = fmaf(bv[u2], -c2v, s);
                s = fmaf(fx8[u2], -c4, s);
                if (s < best8[u2]) { best8[u2] = s; lab8[u2] = k; }
            }
        }
#pragma unroll
        for (int u2 = 0; u2 < 8; ++u2) {
            if (lab8[u2] != runlab) {
                if (rn > 0) {   // mid-thread run boundary: rare inline flush
                    double* pp = part[runlab];
                    unsafeAtomicAdd(&pp[0], (double)sr);
                    unsafeAtomicAdd(&pp[1], (double)sg);
                    unsafeAtomicAdd(&pp[2], (double)sb);
                    unsafeAtomicAdd(&pp[3], (double)((float)(gy * rn)));  // exact int
                    unsafeAtomicAdd(&pp[4], (double)scol);                 // exact int
                    unsafeAtomicAdd(&pp[5], (double)rn);
                }
                runlab = lab8[u2];
                sr = rr[u2]; sg = gg[u2]; sb = bv[u2]; scol = (float)(gx + u2); rn = 1;
            } else {
                sr += rr[u2]; sg += gg[u2]; sb += bv[u2]; scol += (float)(gx + u2); rn += 1;
            }
        }
    }

    // ---- wave-segmented reduction of final runs ----
    {
        float fsr = sr, fsg = sg, fsb = sb, fscol = scol;
        float fsrow = (float)(gy * rn);
        float frn = (float)rn;
        unsigned long long remaining = __ballot(true);
        while (remaining) {
            int leader = __ffsll((unsigned long long)remaining) - 1;
            int labL = __shfl(runlab, leader);
            bool in = (runlab == labL);
            unsigned long long grp = __ballot(in);
            float a0 = in ? fsr : 0.0f, a1 = in ? fsg : 0.0f, a2 = in ? fsb : 0.0f;
            float a3 = in ? fsrow : 0.0f, a4 = in ? fscol : 0.0f, a5 = in ? frn : 0.0f;
#pragma unroll
            for (int off = 1; off < 64; off <<= 1) {
                a0 += __shfl_xor(a0, off);
                a1 += __shfl_xor(a1, off);
                a2 += __shfl_xor(a2, off);
                a3 += __shfl_xor(a3, off);
                a4 += __shfl_xor(a4, off);
                a5 += __shfl_xor(a5, off);
            }
            if (lane == leader) {
                double* pp = part[labL];
                unsafeAtomicAdd(&pp[0], (double)a0);
                unsafeAtomicAdd(&pp[1], (double)a1);
                unsafeAtomicAdd(&pp[2], (double)a2);
                unsafeAtomicAdd(&pp[3], (double)a3);
                unsafeAtomicAdd(&pp[4], (double)a4);
                unsafeAtomicAdd(&pp[5], (double)a5);
            }
            remaining &= ~grp;
        }
    }
    __syncthreads();

    // ---- flush block partials to this pass's global sums (scale row/col) ----
    double* gp = gsums + ((size_t)it * BATCH + b) * SLOTS;
    for (int i = t; i < SLOTS; i += 256) {
        double v = ((double*)part)[i];
        int slot = i % 6;
        if (slot == 3 || slot == 4) v *= (double)ratiof;
        if (v != 0.0) unsafeAtomicAdd(&gp[i], v);
    }
}

// ================= persistent path: one kernel, 11 passes, per-image barrier =====
__global__ void __launch_bounds__(256) persist_light(
        const float* __restrict__ x, double* __restrict__ gsums,
        unsigned* __restrict__ cnt, float* __restrict__ out, float ratiof) {
    __shared__ float cen[K_SEG][6];
    __shared__ float cmax[K_SEG];
    __shared__ double part[K_SEG][6];
    __shared__ int klist4[4][52];
    __shared__ int ncand4[4];

    int t = threadIdx.x;
    int blk = blockIdx.x;
    int b = blk >> 6;
    int tid6 = blk & 63;
    int ty = tid6 >> 3, tx = tid6 & 7;
    const float* xb = x + (size_t)b * 3 * NPIX;

    for (int it = 0; it < NPASS; ++it) {
        pass_body(xb, gsums, it, b, tx, ty, t, ratiof, cen, cmax, part, klist4, ncand4);

        // ---- per-image software barrier (64 blocks) ----
        if (t == 0) {
            unsigned* c = &cnt[it * BATCH + b];
            __threadfence();
            __hip_atomic_fetch_add(c, 1u, __ATOMIC_ACQ_REL, __HIP_MEMORY_SCOPE_AGENT);
            unsigned spins = 0;
            while (__hip_atomic_load(c, __ATOMIC_ACQUIRE, __HIP_MEMORY_SCOPE_AGENT)
                   < (unsigned)BLK_PER_IMG) {
                __builtin_amdgcn_s_sleep(2);
                if (++spins > (1u << 22)) break;  // safety valve: fail, don't hang
            }
        }
        __syncthreads();
    }

    // ---- per-image finalize ----
    if (tid6 == 0 && t == 0) {
        const double* gp = gsums + ((size_t)ITERS * BATCH + b) * SLOTS;
        double sr = 0.0, sg = 0.0, sb = 0.0;
        for (int k = 0; k < K_SEG; ++k) {
            const double* s = gp + k * 6;
            double cv = s[5];
            float cntf = (float)(cv > 1.0 ? cv : 1.0);
            float wf = 1.0f / cntf;  // fp32 rounding like reference w
            sr += s[0] * (double)wf;
            sg += s[1] * (double)wf;
            sb += s[2] * (double)wf;
        }
        double mr = sr / (double)NPIX, mg = sg / (double)NPIX, mb = sb / (double)NPIX;
        double Drg = (mr - mg) * (mr - mg);
        double Drb = (mr - mb) * (mr - mb);
        double Dgb = (mb - mg) * (mb - mg);
        out[b] = (float)sqrt(Drg * Drg + Drb * Drb + Dgb * Dgb);
    }
}

// ================= fallback: R9's proven 214us multi-kernel path =================

__global__ void __launch_bounds__(256) assign_fused(
        const float* __restrict__ x, double* __restrict__ gsums,
        int it, float ratiof) {
    __shared__ float cen[K_SEG][6];
    __shared__ float cmax[K_SEG];
    __shared__ double part[K_SEG][6];
    __shared__ int klist4[4][52];
    __shared__ int ncand4[4];
    int t = threadIdx.x;
    int tx = blockIdx.x, ty = blockIdx.y, b = blockIdx.z;
    const float* xb = x + (size_t)b * 3 * NPIX;
    pass_body(xb, gsums, it, b, tx, ty, t, ratiof, cen, cmax, part, klist4, ncand4);
}

__global__ void finalize_kernel(const double* __restrict__ gsums, float* __restrict__ out) {
    int t = threadIdx.x;
    if (t < BATCH) {
        const double* gp = gsums + ((size_t)ITERS * BATCH + t) * SLOTS;
        double sr = 0.0, sg = 0.0, sb = 0.0;
        for (int k = 0; k < K_SEG; ++k) {
            const double* s = gp + k * 6;
            double cv = s[5];
            float cntf = (float)(cv > 1.0 ? cv : 1.0);
            float wf = 1.0f / cntf;
            sr += s[0] * (double)wf;
            sg += s[1] * (double)wf;
            sb += s[2] * (double)wf;
        }
        double mr = sr / (double)NPIX, mg = sg / (double)NPIX, mb = sb / (double)NPIX;
        double Drg = (mr - mg) * (mr - mg);
        double Drb = (mr - mb) * (mr - mb);
        double Dgb = (mb - mg) * (mb - mg);
        out[t] = (float)sqrt(Drg * Drg + Drb * Drb + Dgb * Dgb);
    }
}

extern "C" void kernel_launch(void* const* d_in, const int* in_sizes, int n_in,
                              void* d_out, int out_size, void* d_ws, size_t ws_size,
                              hipStream_t stream) {
    const float* x = (const float*)d_in[0];
    float* out = (float*)d_out;
    char* ws = (char*)d_ws;

    double S = sqrt((double)NPIX / (double)K_SEG);
    float ratiof = (float)(10.0 / S);

    const size_t gbytes = (size_t)TOTAL_SLOTS * sizeof(double);           // 422400
    const size_t need = gbytes + (size_t)NPASS * BATCH * sizeof(unsigned);

    // host-side capability gate (pure queries: graph-capture-safe).
    int dev = 0, ncu = 0, occ = 0;
    (void)hipGetDevice(&dev);
    (void)hipDeviceGetAttribute(&ncu, hipDeviceAttributeMultiprocessorCount, dev);
    (void)hipOccupancyMaxActiveBlocksPerMultiprocessor(&occ, persist_light, 256, 0);

    if ((long)occ * (long)ncu >= GRID_BLKS && ws_size >= need) {
        double* gsums = (double*)ws;
        unsigned* cnt = (unsigned*)(ws + gbytes);
        int nwords = (int)(need / 4);
        zero_ws<<<(nwords + 255) / 256, 256, 0, stream>>>((unsigned*)ws, nwords);
        persist_light<<<GRID_BLKS, 256, 0, stream>>>(x, gsums, cnt, out, ratiof);
        return;
    }

    if (ws_size >= gbytes) {   // fallback: R9's proven 214us sequence
        double* gsums = (double*)ws;
        int nwords = (int)(gbytes / 4);
        zero_ws<<<(nwords + 255) / 256, 256, 0, stream>>>((unsigned*)ws, nwords);
        dim3 agrid(W_IMG / 64, H_IMG / 64, BATCH);
        for (int it = 0; it < NPASS; ++it)
            assign_fused<<<agrid, 256, 0, stream>>>(x, gsums, it, ratiof);
        finalize_kernel<<<1, 64, 0, stream>>>(gsums, out);
    }
}